// Round 5
// baseline (4076.124 us; speedup 1.0000x reference)
//
#include <hip/hip_runtime.h>

#define NB 256
#define NT 1024
#define NUNF 6
#define NSP 20
#define MCMAX 8
#define MIMAX 12
#define L2E 1.44269504088896340736f

typedef const float* fp;

extern "C" __device__ float __ocml_exp2_f32(float);
__device__ __forceinline__ float frcp(float x) { return __builtin_amdgcn_rcpf(x); }
__device__ __forceinline__ float ex2(float x) { return __ocml_exp2_f32(x); }

struct Tables {
    int ns;                      // needed slot count (<=20)
    int mc;                      // max command in-degree over needed units
    int unit_of_slot[NSP];
    float cmt[NSP];
    int   ce_pre[NSP * MCMAX];   // chain edges: pre slot id
    float ce_a[NSP * MCMAX], ce_b[NSP * MCMAX], ce_w[NSP * MCMAX], ce_e[NSP * MCMAX];
    int   ki_cnt[NSP];           // inter edges per slot (for fold)
    int   ki_i[NSP * MIMAX];
    float ki_a[NSP * MIMAX], ki_b[NSP * MIMAX], ki_w[NSP * MIMAX], ki_e[NSP * MIMAX];
};

// ws layout: 0 Tables | 16384 istate (12KB) | 32768 vstate (32KB) |
//            65536: sensC CT*64KB ; interP CT*48KB ; pnd CT*240KB
#define WS_ISTATE 16384
#define WS_VSTATE 32768
#define WS_DATA   65536

// ---------------- K0: build needed-set + compact tables (single thread) ----------------
__global__ void build_tables(fp w_syn, fp mu, fp sigma, fp erev, const int* spm,
                             fp cm, Tables* T) {
    if (threadIdx.x != 0 || blockIdx.x != 0) return;
    bool needed[20];
    for (int j = 0; j < 20; ++j) needed[j] = false;
    needed[0] = true;
    for (int it = 0; it < 20; ++it)
        for (int i = 0; i < 20; ++i)
            for (int j = 0; j < 20; ++j)
                if (spm[i * 32 + j] && needed[j]) needed[i] = true;
    int slot_of[20];
    int ns = 0;
    for (int j = 0; j < 20; ++j) slot_of[j] = 0;
    for (int j = 0; j < 20; ++j)
        if (needed[j]) { T->unit_of_slot[ns] = j; slot_of[j] = ns; ++ns; }
    T->ns = ns;
    int mc = 1;
    for (int s = 0; s < ns; ++s) {
        int j = T->unit_of_slot[s];
        T->cmt[s] = cm[j] * (float)NUNF;
        int cc = 0, ci = 0;
        for (int i = 0; i < 32; ++i) {
            int p = i * 32 + j;
            if (!spm[p]) continue;
            float sg = sigma[p], w = w_syn[p];
            if (i < 20) {
                int sl = s * MCMAX + cc;
                T->ce_pre[sl] = slot_of[i];
                T->ce_a[sl] = -sg * L2E; T->ce_b[sl] = sg * mu[p] * L2E;
                T->ce_w[sl] = w; T->ce_e[sl] = w * erev[p];
                ++cc;
            } else {
                int sl = s * MIMAX + ci;
                T->ki_i[sl] = i - 20;
                T->ki_a[sl] = -sg * L2E; T->ki_b[sl] = sg * mu[p] * L2E;
                T->ki_w[sl] = w; T->ki_e[sl] = w * erev[p];
                ++ci;
            }
        }
        for (int c = cc; c < MCMAX; ++c) {
            int sl = s * MCMAX + c;
            T->ce_pre[sl] = 0; T->ce_a[sl] = 0.f; T->ce_b[sl] = 0.f;
            T->ce_w[sl] = 0.f; T->ce_e[sl] = 0.f;
        }
        T->ki_cnt[s] = ci;
        mc = max(mc, cc);
    }
    for (int s = ns; s < NSP; ++s) {
        T->cmt[s] = 1.f; T->ki_cnt[s] = 0; T->unit_of_slot[s] = 0;
        for (int c = 0; c < MCMAX; ++c) {
            int sl = s * MCMAX + c;
            T->ce_pre[sl] = 0; T->ce_a[sl] = 0.f; T->ce_b[sl] = 0.f;
            T->ce_w[sl] = 0.f; T->ce_e[sl] = 0.f;
        }
    }
    T->mc = mc;
}

// ---------------- K1: dense stack + sensory gate sums (leak/cm folded) ----------------
__global__ __launch_bounds__(256) void dense_sens(
    fp x, fp d1w, fp d1b, fp d2w, fp d2b, fp iw, fp ib,
    fp sw, fp smu, fp ssg, fp serev, const int* smask,
    fp gleak, fp vleak, fp cm,
    float2* sensC, int t0, int CT) {
    __shared__ float W1s[256], b1s[128], W2s[4096], b2s[32], iws[32], ibs[32];
    __shared__ float gss[1024], gnm[1024], gwm[1024], gwe[1024];
    __shared__ float num0[32], den0[32];
    __shared__ float hbuf[8][128];
    __shared__ float ibuf[8][32];
    int tid = threadIdx.x;
    if (tid < 256) W1s[tid] = d1w[tid];
    if (tid < 128) b1s[tid] = d1b[tid];
    for (int p = tid; p < 4096; p += 256) W2s[p] = d2w[p];
    if (tid < 32) {
        b2s[tid] = d2b[tid]; iws[tid] = iw[tid]; ibs[tid] = ib[tid];
        float gl = gleak[tid];
        num0[tid] = gl * vleak[tid];
        den0[tid] = cm[tid] * (float)NUNF + gl + 1e-8f;
    }
    for (int p = tid; p < 1024; p += 256) {
        float s = ssg[p];
        float wv = sw[p];
        gss[p] = -s * L2E;
        gnm[p] = s * smu[p] * L2E;
        gwm[p] = wv * (float)smask[p];
        gwe[p] = wv * serev[p];
    }
    __syncthreads();
    int g = tid >> 5, j = tid & 31;
    const float2* x2 = (const float2*)x;
    int niters = CT * 32;
    for (int itg = blockIdx.x; itg < niters; itg += gridDim.x) {
        int cg = itg * 8 + g;             // cg = lt*256 + b
        int lt = cg >> 8, b = cg & 255;
        int t = t0 + lt;
        float2 xv = x2[b * NT + t];
#pragma unroll
        for (int r = 0; r < 4; ++r) {
            int k = j + 32 * r;
            float hk = fmaf(xv.y, W1s[128 + k], fmaf(xv.x, W1s[k], b1s[k]));
            hbuf[g][k] = hk > 0.f ? hk : 0.f;
        }
        float a0 = 0.f, a1 = 0.f, a2 = 0.f, a3 = 0.f;
#pragma unroll 8
        for (int k = 0; k < 128; k += 4) {
            a0 = fmaf(hbuf[g][k],     W2s[k * 32 + j],       a0);
            a1 = fmaf(hbuf[g][k + 1], W2s[(k + 1) * 32 + j], a1);
            a2 = fmaf(hbuf[g][k + 2], W2s[(k + 2) * 32 + j], a2);
            a3 = fmaf(hbuf[g][k + 3], W2s[(k + 3) * 32 + j], a3);
        }
        float acc = b2s[j] + ((a0 + a1) + (a2 + a3));
        ibuf[g][j] = fmaf(acc, iws[j], ibs[j]);
        float wn = num0[j], wd = den0[j];
        for (int i = 0; i < 32; ++i) {
            int p = i * 32 + j;
            float xg = fmaf(ibuf[g][i], gss[p], gnm[p]);
            float sg = frcp(1.f + ex2(xg));
            wn = fmaf(gwe[p], sg, wn);
            wd = fmaf(gwm[p], sg, wd);
        }
        sensC[cg * 32 + j] = make_float2(wn, wd);
    }
}

// ---------------- K2: inter-neuron affine scan over t ----------------
__global__ __launch_bounds__(64) void inter_scan(const float2* __restrict__ sensC, fp cm,
                                                 float4* interP, float* interState,
                                                 int t0, int CT) {
    int lane = threadIdx.x;
    int p = lane & 15, q = lane >> 4;
    int b = blockIdx.x * 4 + q;
    bool act = p < 12;
    int j = 20 + (act ? p : 0);
    float cmt = cm[j] * (float)NUNF;
    float v = (t0 == 0) ? 0.f : (act ? interState[b * 12 + p] : 0.f);
    const float2* sp = sensC + b * 32 + j;
    float4* op = interP + b * 12 + (act ? p : 0);
    for (int lt = 0; lt < CT; ++lt) {
        float2 s = sp[(size_t)lt * (NB * 32)];
        float r = frcp(s.y);
        float A = cmt * r, B = s.x * r;
        if (act) op[(size_t)lt * (NB * 12)] = make_float4(v, A, B, 0.f);
#pragma unroll
        for (int u = 0; u < NUNF; ++u) v = fmaf(A, v, B);
    }
    if (act) interState[b * 12 + p] = v;
}

// ---------------- K3: fold inter gates into per-unfold pn/pd (parallel b,t,slot) ----------------
__global__ __launch_bounds__(256) void fold_pnd(const float2* __restrict__ sensC,
                                                const float4* __restrict__ interP,
                                                const Tables* __restrict__ T,
                                                float2* __restrict__ pnd, int CT) {
    int ns = T->ns;
    long total = (long)CT * NB * ns;
    long gid = (long)blockIdx.x * 256 + threadIdx.x;
    if (gid >= total) return;
    int sl = (int)(gid % ns);
    long r = gid / ns;
    int b = (int)(r % NB);
    int lt = (int)(r / NB);
    int unit = T->unit_of_slot[sl];
    float2 sc = sensC[((long)lt * NB + b) * 32 + unit];
    float pn[6], pd[6];
#pragma unroll
    for (int u = 0; u < 6; ++u) { pn[u] = sc.x; pd[u] = sc.y; }
    int kc = T->ki_cnt[sl];
    for (int e = 0; e < kc; ++e) {
        int k = sl * MIMAX + e;
        float4 ip = interP[((long)lt * NB + b) * 12 + T->ki_i[k]];
        float vi = ip.x, A = ip.y, B = ip.z;
        float ga = T->ki_a[k], gb = T->ki_b[k], W = T->ki_w[k], E = T->ki_e[k];
#pragma unroll
        for (int u = 0; u < 6; ++u) {
            float g = frcp(1.f + ex2(fmaf(ga, vi, gb)));
            pn[u] = fmaf(E, g, pn[u]);
            pd[u] = fmaf(W, g, pd[u]);
            vi = fmaf(A, vi, B);
        }
    }
#pragma unroll
    for (int u = 0; u < 6; ++u)
        pnd[((long)(lt * 6 + u) * NB + b) * NSP + sl] = make_float2(pn[u], pd[u]);
}

// ---------------- K4: command chain scan (lane=slot, half-wave=batch) ----------------
template <int MC>
__device__ void chain_impl(const float2* __restrict__ pnd, const Tables* __restrict__ T,
                           float* vstate, fp ow, fp ob, int t0, int CT, float* out) {
    int lane = threadIdx.x;
    int s = lane & 31;
    int b = blockIdx.x * 2 + (lane >> 5);
    int ns = T->ns;
    bool act = s < ns;
    int sl = act ? s : 0;
    float cmt = T->cmt[sl];
    int ap[MC]; float ea[MC], eb[MC], ew[MC], ee[MC];
#pragma unroll
    for (int e = 0; e < MC; ++e) {
        int k = sl * MCMAX + e;
        ap[e] = ((lane & 32) | T->ce_pre[k]) << 2;
        ea[e] = T->ce_a[k]; eb[e] = T->ce_b[k];
        ew[e] = T->ce_w[k]; ee[e] = T->ce_e[k];
    }
    float v = (t0 == 0) ? 0.f : vstate[b * 32 + sl];
    const float2* pb = pnd + (long)b * NSP + sl;
    float2 pc[6], px[6];
#pragma unroll
    for (int u = 0; u < 6; ++u) pc[u] = pb[(long)u * (NB * NSP)];
    for (int t = 0; t < CT; ++t) {
        int t2 = (t + 1 < CT) ? (t + 1) : t;
#pragma unroll
        for (int u = 0; u < 6; ++u) px[u] = pb[(long)(t2 * 6 + u) * (NB * NSP)];
#pragma unroll
        for (int u = 0; u < 6; ++u) {
            float vp[MC];
#pragma unroll
            for (int e = 0; e < MC; ++e)
                vp[e] = __int_as_float(__builtin_amdgcn_ds_bpermute(ap[e], __float_as_int(v)));
            float wn = pc[u].x, wd = pc[u].y;
#pragma unroll
            for (int e = 0; e < MC; ++e) {
                float g = frcp(1.f + ex2(fmaf(ea[e], vp[e], eb[e])));
                wn = fmaf(ee[e], g, wn);
                wd = fmaf(ew[e], g, wd);
            }
            v = fmaf(cmt, v, wn) * frcp(wd);
        }
#pragma unroll
        for (int u = 0; u < 6; ++u) pc[u] = px[u];
    }
    if (act) vstate[b * 32 + sl] = v;
    if (t0 + CT == NT && s == 0) out[b] = fmaf(v, ow[0], ob[0]);
}

__global__ __launch_bounds__(64) void cmd_chain(const float2* __restrict__ pnd,
                                                const Tables* __restrict__ T,
                                                float* vstate, fp ow, fp ob,
                                                int t0, int CT, float* out) {
    int mc = T->mc;
    if (mc <= 2)      chain_impl<2>(pnd, T, vstate, ow, ob, t0, CT, out);
    else if (mc <= 4) chain_impl<4>(pnd, T, vstate, ow, ob, t0, CT, out);
    else if (mc <= 6) chain_impl<6>(pnd, T, vstate, ow, ob, t0, CT, out);
    else              chain_impl<8>(pnd, T, vstate, ow, ob, t0, CT, out);
}

extern "C" void kernel_launch(void* const* d_in, const int* in_sizes, int n_in,
                              void* d_out, int out_size, void* d_ws, size_t ws_size,
                              hipStream_t stream) {
    fp x     = (fp)d_in[0];
    fp d1w   = (fp)d_in[1];
    fp d1b   = (fp)d_in[2];
    fp d2w   = (fp)d_in[3];
    fp d2b   = (fp)d_in[4];
    fp iw    = (fp)d_in[5];
    fp ib    = (fp)d_in[6];
    fp ow    = (fp)d_in[7];
    fp ob    = (fp)d_in[8];
    fp gleak = (fp)d_in[9];
    fp vleak = (fp)d_in[10];
    fp cm    = (fp)d_in[11];
    fp wsyn  = (fp)d_in[12];
    fp mu    = (fp)d_in[13];
    fp sigma = (fp)d_in[14];
    fp erev  = (fp)d_in[15];
    fp sw    = (fp)d_in[16];
    fp smu   = (fp)d_in[17];
    fp ssg   = (fp)d_in[18];
    fp serev = (fp)d_in[19];
    const int* spm   = (const int*)d_in[20];
    const int* smask = (const int*)d_in[21];

    char* wsb = (char*)d_ws;
    Tables* T     = (Tables*)wsb;
    float* istate = (float*)(wsb + WS_ISTATE);
    float* vstate = (float*)(wsb + WS_VSTATE);

    // per-timestep staging: sensC 64KB + interP 48KB + pnd 240KB
    size_t per_t = (size_t)NB * 32 * 8 + (size_t)NB * 12 * 16 + (size_t)NB * NSP * 6 * 8;
    int CT = 1;
    if (ws_size > WS_DATA + per_t) {
        size_t m = (ws_size - WS_DATA) / per_t;
        int ct = 1;
        while (ct < NT && (size_t)(ct * 2) <= m) ct *= 2;
        CT = ct;
    }
    float2* sensC  = (float2*)(wsb + WS_DATA);
    float4* interP = (float4*)(wsb + WS_DATA + (size_t)CT * NB * 32 * 8);
    float2* pnd    = (float2*)(wsb + WS_DATA + (size_t)CT * NB * 32 * 8 + (size_t)CT * NB * 12 * 16);

    build_tables<<<1, 64, 0, stream>>>(wsyn, mu, sigma, erev, spm, cm, T);

    int nch = NT / CT;
    for (int c = 0; c < nch; ++c) {
        int t0 = c * CT;
        int niters = CT * 32;
        int blocks = niters < 2048 ? niters : 2048;
        dense_sens<<<blocks, 256, 0, stream>>>(x, d1w, d1b, d2w, d2b, iw, ib,
                                               sw, smu, ssg, serev, smask,
                                               gleak, vleak, cm, sensC, t0, CT);
        inter_scan<<<NB / 4, 64, 0, stream>>>(sensC, cm, interP, istate, t0, CT);
        long total = (long)CT * NB * NSP;   // upper bound on ns for grid sizing
        int fblocks = (int)((total + 255) / 256);
        fold_pnd<<<fblocks, 256, 0, stream>>>(sensC, interP, T, pnd, CT);
        cmd_chain<<<NB / 2, 64, 0, stream>>>(pnd, T, vstate, ow, ob, t0, CT, (float*)d_out);
    }
}

// Round 6
// 790.869 us; speedup vs baseline: 5.1540x; 5.1540x over previous
//
#include <hip/hip_runtime.h>

#define NB 256
#define NT 1024
#define NUNF 6
#define TB 64
#define L2E 1.44269504088896340736f

typedef const float* fp;

extern "C" __device__ float __ocml_exp2_f32(float);
__device__ __forceinline__ float frcp(float x) { return __builtin_amdgcn_rcpf(x); }
__device__ __forceinline__ float ex2(float x) { return __ocml_exp2_f32(x); }
__device__ __forceinline__ float sgm(float a, float b, float v) { return frcp(1.f + ex2(fmaf(a, v, b))); }

struct Tables {
    int ngroups, npos, pad0, pad1;
    int grp_start[21];
    int ord[20];
    int pos[20];
    float cmt[20];
    float icmt[12];
    int ncp[20], nip[20], ngp[20];
    int   cp_pre[20][8];
    float cp_a[20][8], cp_b[20][8], cp_w[20][8], cp_e[20][8];
    int   ip_i[20][12];
    float ip_a[20][12], ip_b[20][12], ip_w[20][12], ip_e[20][12];
    int   gp_pre[20][6];
    float gp_a[20][6], gp_b[20][6], gp_w[20][6], gp_e[20][6];
};

#define WS_VSTATE 16384
#define WS_SENSC  65536

// ---------------- K0: wiring analysis, lane-parallel in LDS ----------------
__global__ void build_tables(fp wsyn, fp mu, fp sigma, fp erev, const int* spm, fp cm, Tables* T) {
    __shared__ int   spmL[1024];
    __shared__ float wL[1024], muL[1024], sgL[1024], evL[1024];
    __shared__ float cmL[32];
    __shared__ int premaskL[20], ancL[20], rootL[20], depUL[20], keyL[20], posL[20], ordL[20];
    __shared__ int neededS;
    int tid = threadIdx.x;
    for (int k = tid; k < 1024; k += 64) {
        spmL[k] = spm[k]; wL[k] = wsyn[k]; muL[k] = mu[k]; sgL[k] = sigma[k]; evL[k] = erev[k];
    }
    if (tid < 32) cmL[tid] = cm[tid];
    __syncthreads();
    if (tid < 20) {
        int pm = 0;
        for (int i = 0; i < 20; ++i) if (spmL[i * 32 + tid]) pm |= 1 << i;
        premaskL[tid] = pm;
        ancL[tid] = pm;
    }
    __syncthreads();
    for (int it = 0; it < 20; ++it) {         // ancestor closure
        int a = 0;
        if (tid < 20) {
            a = ancL[tid];
            int pm = premaskL[tid];
            for (int i = 0; i < 20; ++i) if ((pm >> i) & 1) a |= ancL[i];
        }
        __syncthreads();
        if (tid < 20) ancL[tid] = a;
        __syncthreads();
    }
    if (tid == 0) neededS = ancL[0] | 1;
    __syncthreads();
    int needed = neededS;
    if (tid < 20) {                            // SCC root = min mutual-reach partner
        int r = tid;
        if ((needed >> tid) & 1) {
            int aj = ancL[tid];
            for (int i = 0; i < 20; ++i)
                if (i < r && ((needed >> i) & 1) && ((aj >> i) & 1) && ((ancL[i] >> tid) & 1)) r = i;
        }
        rootL[tid] = r;
        depUL[tid] = 0;
    }
    __syncthreads();
    for (int it = 0; it < 21; ++it) {          // condensation topo depth
        int d = 0;
        if (tid < 20 && ((needed >> tid) & 1)) {
            int pm = premaskL[tid], myr = rootL[tid];
            for (int i = 0; i < 20; ++i)
                if (((pm >> i) & 1) && rootL[i] != myr) d = max(d, depUL[i] + 1);
        }
        __syncthreads();
        if (tid < 20 && d > depUL[tid]) depUL[tid] = d;
        __syncthreads();
    }
    if (tid < 20) {                            // sort key: (group depth, root)
        int key = 0x7FFFFFFF;
        if ((needed >> tid) & 1) {
            int myr = rootL[tid], dg = 0;
            for (int i = 0; i < 20; ++i)
                if (((needed >> i) & 1) && rootL[i] == myr) dg = max(dg, depUL[i]);
            key = dg * 32 + myr;
        }
        keyL[tid] = key;
    }
    __syncthreads();
    if (tid < 20) {                            // stable rank -> position
        int mykey = keyL[tid];
        int p = 0;
        for (int k = 0; k < 20; ++k)
            if (keyL[k] < mykey || (keyL[k] == mykey && k < tid)) ++p;
        posL[tid] = p;
        if (p < 20) ordL[p] = tid;
    }
    __syncthreads();
    if (tid == 0) {
        int npos = __popc(needed & 0xFFFFF);
        T->npos = npos;
        int ng = 0, prevkey = -1;
        for (int p = 0; p < npos; ++p) {
            int u = ordL[p];
            if (keyL[u] != prevkey) { T->grp_start[ng] = p; ++ng; prevkey = keyL[u]; }
        }
        T->ngroups = ng;
        for (int g = ng; g <= 20; ++g) T->grp_start[g] = npos;
        for (int p = 0; p < 20; ++p) T->ord[p] = (p < npos) ? ordL[p] : 0;
        for (int j = 0; j < 20; ++j) T->pos[j] = posL[j];
    }
    __syncthreads();
    if (tid < 20) {                            // per-unit edge tables (from LDS)
        int j = tid, cc = 0, ci = 0, cg = 0;
        T->cmt[j] = cmL[j] * (float)NUNF;
        if ((needed >> j) & 1) {
            int myr = rootL[j];
            int mystart = posL[myr];
            for (int i = 0; i < 32; ++i) {
                int p = i * 32 + j;
                if (!spmL[p]) continue;
                float sg = sgL[p];
                float a = -sg * L2E, b = sg * muL[p] * L2E;
                float w = wL[p], e = w * evL[p];
                if (i >= 20) {
                    T->ip_i[j][ci] = i - 20;
                    T->ip_a[j][ci] = a; T->ip_b[j][ci] = b; T->ip_w[j][ci] = w; T->ip_e[j][ci] = e;
                    ++ci;
                } else if (rootL[i] == myr) {
                    T->gp_pre[j][cg] = posL[i] - mystart;
                    T->gp_a[j][cg] = a; T->gp_b[j][cg] = b; T->gp_w[j][cg] = w; T->gp_e[j][cg] = e;
                    ++cg;
                } else {
                    T->cp_pre[j][cc] = posL[i];
                    T->cp_a[j][cc] = a; T->cp_b[j][cc] = b; T->cp_w[j][cc] = w; T->cp_e[j][cc] = e;
                    ++cc;
                }
            }
        }
        T->ncp[j] = cc; T->nip[j] = ci; T->ngp[j] = cg;
    }
    if (tid < 12) T->icmt[tid] = cmL[20 + tid] * (float)NUNF;
}

// ---------------- K1: dense stack + sensory gate sums (leak/cm folded) ----------------
__global__ __launch_bounds__(256) void dense_sens(
    fp x, fp d1w, fp d1b, fp d2w, fp d2b, fp iw, fp ib,
    fp sw, fp smu, fp ssg, fp serev, const int* smask,
    fp gleak, fp vleak, fp cm,
    float2* sensC, int t0, int CT) {
    __shared__ float W1s[256], b1s[128], W2s[4096], b2s[32], iws[32], ibs[32];
    __shared__ float gss[1024], gnm[1024], gwm[1024], gwe[1024];
    __shared__ float num0[32], den0[32];
    __shared__ float hbuf[8][128];
    __shared__ float ibuf[8][32];
    int tid = threadIdx.x;
    if (tid < 256) W1s[tid] = d1w[tid];
    if (tid < 128) b1s[tid] = d1b[tid];
    for (int p = tid; p < 4096; p += 256) W2s[p] = d2w[p];
    if (tid < 32) {
        b2s[tid] = d2b[tid]; iws[tid] = iw[tid]; ibs[tid] = ib[tid];
        float gl = gleak[tid];
        num0[tid] = gl * vleak[tid];
        den0[tid] = cm[tid] * (float)NUNF + gl + 1e-8f;
    }
    for (int p = tid; p < 1024; p += 256) {
        float s = ssg[p];
        float wv = sw[p];
        gss[p] = -s * L2E;
        gnm[p] = s * smu[p] * L2E;
        gwm[p] = wv * (float)smask[p];
        gwe[p] = wv * serev[p];
    }
    __syncthreads();
    int g = tid >> 5, j = tid & 31;
    const float2* x2 = (const float2*)x;
    int niters = CT * 32;
    for (int itg = blockIdx.x; itg < niters; itg += gridDim.x) {
        int cg = itg * 8 + g;
        int lt = cg >> 8, b = cg & 255;
        int t = t0 + lt;
        float2 xv = x2[b * NT + t];
#pragma unroll
        for (int r = 0; r < 4; ++r) {
            int k = j + 32 * r;
            float hk = fmaf(xv.y, W1s[128 + k], fmaf(xv.x, W1s[k], b1s[k]));
            hbuf[g][k] = hk > 0.f ? hk : 0.f;
        }
        float a0 = 0.f, a1 = 0.f, a2 = 0.f, a3 = 0.f;
#pragma unroll 8
        for (int k = 0; k < 128; k += 4) {
            a0 = fmaf(hbuf[g][k],     W2s[k * 32 + j],       a0);
            a1 = fmaf(hbuf[g][k + 1], W2s[(k + 1) * 32 + j], a1);
            a2 = fmaf(hbuf[g][k + 2], W2s[(k + 2) * 32 + j], a2);
            a3 = fmaf(hbuf[g][k + 3], W2s[(k + 3) * 32 + j], a3);
        }
        float acc = b2s[j] + ((a0 + a1) + (a2 + a3));
        ibuf[g][j] = fmaf(acc, iws[j], ibs[j]);
        float wn = num0[j], wd = den0[j];
        for (int i = 0; i < 32; ++i) {
            int p = i * 32 + j;
            float sg = frcp(1.f + ex2(fmaf(ibuf[g][i], gss[p], gnm[p])));
            wn = fmaf(gwe[p], sg, wn);
            wd = fmaf(gwm[p], sg, wd);
        }
        sensC[cg * 32 + j] = make_float2(wn, wd);
    }
}

// ---------------- K2: per-batch topological solver ----------------
__global__ __launch_bounds__(256) void solve(const float2* __restrict__ sensC,
                                             const Tables* __restrict__ Tg,
                                             fp ow, fp ob, float* vstate,
                                             int t0, int CT, float* out) {
    __shared__ Tables TL;
    __shared__ float2 sT[TB * 33];
    __shared__ float viter[TB * 13];
    __shared__ float vtraj[20 * TB * 7];
    __shared__ float2 pnpd[6 * TB * 7];
    __shared__ float gstate[20], istate[12], newvS[8];
    int tid = threadIdx.x;
    int b = blockIdx.x;
    {
        const int nw = (int)(sizeof(Tables) / 4);
        const int* src = (const int*)Tg;
        int* dst = (int*)&TL;
        for (int k = tid; k < nw; k += 256) dst[k] = src[k];
    }
    if (tid < 20) gstate[tid] = (t0 == 0) ? 0.f : vstate[b * 32 + tid];
    if (tid < 12) istate[tid] = (t0 == 0) ? 0.f : vstate[b * 32 + 20 + tid];
    __syncthreads();
    int ntiles = CT / TB;
    bool lastChunk = (t0 + CT == NT);
    int t = tid & (TB - 1), q = tid >> 6;
    for (int tile = 0; tile < ntiles; ++tile) {
        for (int e = tid; e < TB * 32; e += 256) {
            int tt = e >> 5, j = e & 31;
            sT[tt * 33 + j] = sensC[((size_t)(tile * TB + tt) * NB + b) * 32 + j];
        }
        __syncthreads();
        if (tid < 12) {                       // inter trajectories (affine)
            float v = istate[tid];
            float ic = TL.icmt[tid];
            for (int tt = 0; tt < TB; ++tt) {
                float2 si = sT[tt * 33 + 20 + tid];
                viter[tt * 13 + tid] = v;
                float r = frcp(si.y);
                float A = ic * r, B = si.x * r;
#pragma unroll
                for (int u = 0; u < NUNF; ++u) v = fmaf(A, v, B);
            }
            istate[tid] = v;
        }
        __syncthreads();
        int ngroups = TL.ngroups;
        for (int g = 0; g < ngroups; ++g) {
            int gs = TL.grp_start[g], ge = TL.grp_start[g + 1], gsz = ge - gs;
            for (int m = q; m < gsz; m += 4) {      // fold resolved pres
                int pos = gs + m, unit = TL.ord[pos];
                float2 sc = sT[t * 33 + unit];
                float pn[NUNF], pd[NUNF];
#pragma unroll
                for (int u = 0; u < NUNF; ++u) { pn[u] = sc.x; pd[u] = sc.y; }
                int ncp = TL.ncp[unit];
                for (int e = 0; e < ncp; ++e) {
                    float a = TL.cp_a[unit][e], b2 = TL.cp_b[unit][e];
                    float w = TL.cp_w[unit][e], ev = TL.cp_e[unit][e];
                    int pp = TL.cp_pre[unit][e];
#pragma unroll
                    for (int u = 0; u < NUNF; ++u) {
                        float gq = sgm(a, b2, vtraj[(pp * TB + t) * 7 + u]);
                        pn[u] = fmaf(ev, gq, pn[u]);
                        pd[u] = fmaf(w, gq, pd[u]);
                    }
                }
                int nip = TL.nip[unit];
                for (int e = 0; e < nip; ++e) {
                    float a = TL.ip_a[unit][e], b2 = TL.ip_b[unit][e];
                    float w = TL.ip_w[unit][e], ev = TL.ip_e[unit][e];
                    int ii = TL.ip_i[unit][e];
                    float2 si = sT[t * 33 + 20 + ii];
                    float r = frcp(si.y);
                    float A = TL.icmt[ii] * r, B = si.x * r;
                    float vi = viter[t * 13 + ii];
#pragma unroll
                    for (int u = 0; u < NUNF; ++u) {
                        float gq = sgm(a, b2, vi);
                        pn[u] = fmaf(ev, gq, pn[u]);
                        pd[u] = fmaf(w, gq, pd[u]);
                        vi = fmaf(A, vi, B);
                    }
                }
                bool aff = (gsz == 1) && (TL.ngp[unit] == 0);
                float cmtv = TL.cmt[unit];
#pragma unroll
                for (int u = 0; u < NUNF; ++u) {
                    if (aff) {
                        float r = frcp(pd[u]);
                        pnpd[(m * TB + t) * 7 + u] = make_float2(cmtv * r, pn[u] * r);
                    } else {
                        pnpd[(m * TB + t) * 7 + u] = make_float2(pn[u], pd[u]);
                    }
                }
            }
            __syncthreads();
            if (tid == 0) {                          // sequential group scan
                if (gsz == 1) {
                    int unit = TL.ord[gs];
                    float v = gstate[gs];
                    if (TL.ngp[unit] == 0) {         // pure affine
                        for (int tt = 0; tt < TB; ++tt) {
                            float2 ab0 = pnpd[tt * 7 + 0], ab1 = pnpd[tt * 7 + 1], ab2 = pnpd[tt * 7 + 2];
                            float2 ab3 = pnpd[tt * 7 + 3], ab4 = pnpd[tt * 7 + 4], ab5 = pnpd[tt * 7 + 5];
                            float* vt = &vtraj[(gs * TB + tt) * 7];
                            vt[0] = v; v = fmaf(ab0.x, v, ab0.y);
                            vt[1] = v; v = fmaf(ab1.x, v, ab1.y);
                            vt[2] = v; v = fmaf(ab2.x, v, ab2.y);
                            vt[3] = v; v = fmaf(ab3.x, v, ab3.y);
                            vt[4] = v; v = fmaf(ab4.x, v, ab4.y);
                            vt[5] = v; v = fmaf(ab5.x, v, ab5.y);
                        }
                    } else {                         // self-loop
                        float a = TL.gp_a[unit][0], b2 = TL.gp_b[unit][0];
                        float w = TL.gp_w[unit][0], ev = TL.gp_e[unit][0];
                        float cmtv = TL.cmt[unit];
                        for (int tt = 0; tt < TB; ++tt) {
                            float* vt = &vtraj[(gs * TB + tt) * 7];
#pragma unroll
                            for (int u = 0; u < NUNF; ++u) {
                                vt[u] = v;
                                float2 pp = pnpd[tt * 7 + u];
                                float gq = sgm(a, b2, v);
                                float wn = fmaf(ev, gq, pp.x), wd = fmaf(w, gq, pp.y);
                                v = fmaf(cmtv, v, wn) * frcp(wd);
                            }
                        }
                    }
                    gstate[gs] = v;
                    if (lastChunk && tile == ntiles - 1 && unit == 0)
                        out[b] = fmaf(v, ow[0], ob[0]);
                } else {                             // general SCC (LDS, rare)
                    for (int tt = 0; tt < TB; ++tt) {
#pragma unroll
                        for (int u = 0; u < NUNF; ++u) {
                            for (int m = 0; m < gsz; ++m)
                                vtraj[((gs + m) * TB + tt) * 7 + u] = gstate[gs + m];
                            for (int m = 0; m < gsz; ++m) {
                                int unit = TL.ord[gs + m];
                                float2 pp = pnpd[(m * TB + tt) * 7 + u];
                                float wn = pp.x, wd = pp.y;
                                int ngpu = TL.ngp[unit];
                                for (int e = 0; e < ngpu; ++e) {
                                    float vp = gstate[gs + TL.gp_pre[unit][e]];
                                    float gq = sgm(TL.gp_a[unit][e], TL.gp_b[unit][e], vp);
                                    wn = fmaf(TL.gp_e[unit][e], gq, wn);
                                    wd = fmaf(TL.gp_w[unit][e], gq, wd);
                                }
                                newvS[m] = fmaf(TL.cmt[unit], gstate[gs + m], wn) * frcp(wd);
                            }
                            for (int m = 0; m < gsz; ++m) gstate[gs + m] = newvS[m];
                        }
                    }
                    if (lastChunk && tile == ntiles - 1)
                        for (int m = 0; m < gsz; ++m)
                            if (TL.ord[gs + m] == 0) out[b] = fmaf(gstate[gs + m], ow[0], ob[0]);
                }
            }
            __syncthreads();
        }
    }
    if (tid < 20) vstate[b * 32 + tid] = gstate[tid];
    if (tid < 12) vstate[b * 32 + 20 + tid] = istate[tid];
}

extern "C" void kernel_launch(void* const* d_in, const int* in_sizes, int n_in,
                              void* d_out, int out_size, void* d_ws, size_t ws_size,
                              hipStream_t stream) {
    fp x     = (fp)d_in[0];
    fp d1w   = (fp)d_in[1];
    fp d1b   = (fp)d_in[2];
    fp d2w   = (fp)d_in[3];
    fp d2b   = (fp)d_in[4];
    fp iw    = (fp)d_in[5];
    fp ib    = (fp)d_in[6];
    fp ow    = (fp)d_in[7];
    fp ob    = (fp)d_in[8];
    fp gleak = (fp)d_in[9];
    fp vleak = (fp)d_in[10];
    fp cm    = (fp)d_in[11];
    fp wsyn  = (fp)d_in[12];
    fp mu    = (fp)d_in[13];
    fp sigma = (fp)d_in[14];
    fp erev  = (fp)d_in[15];
    fp sw    = (fp)d_in[16];
    fp smu   = (fp)d_in[17];
    fp ssg   = (fp)d_in[18];
    fp serev = (fp)d_in[19];
    const int* spm   = (const int*)d_in[20];
    const int* smask = (const int*)d_in[21];

    char* wsb = (char*)d_ws;
    Tables* T     = (Tables*)wsb;
    float* vstate = (float*)(wsb + WS_VSTATE);
    float2* sensC = (float2*)(wsb + WS_SENSC);

    size_t per_t = (size_t)NB * 32 * sizeof(float2);   // 65536 B
    int CT = TB;
    if (ws_size > WS_SENSC) {
        size_t m = (ws_size - WS_SENSC) / per_t;
        int ct = TB;
        while (ct < NT && (size_t)(ct * 2) <= m) ct *= 2;
        CT = ct;
    }

    build_tables<<<1, 64, 0, stream>>>(wsyn, mu, sigma, erev, spm, cm, T);

    int nch = NT / CT;
    for (int c = 0; c < nch; ++c) {
        int t0 = c * CT;
        int niters = CT * 32;
        int blocks = niters < 2048 ? niters : 2048;
        dense_sens<<<blocks, 256, 0, stream>>>(x, d1w, d1b, d2w, d2b, iw, ib,
                                               sw, smu, ssg, serev, smask,
                                               gleak, vleak, cm, sensC, t0, CT);
        solve<<<NB, 256, 0, stream>>>(sensC, T, ow, ob, vstate, t0, CT, (float*)d_out);
    }
}